// Round 13
// baseline (186.306 us; speedup 1.0000x reference)
//
#include <hip/hip_runtime.h>
#include <hip/hip_bf16.h>

typedef __attribute__((ext_vector_type(8))) short short8;
typedef __attribute__((ext_vector_type(4))) float f32x4;
typedef __attribute__((ext_vector_type(4))) int   i32x4;

#define NTOP 1000
#define KC   256
#define MROWS 40000
#define MBLK  64
#define WS_NEED 5652480   // colsum 8K + Bp 512K + Cb 5.12M

static __device__ __forceinline__ unsigned short f2bf(float x) {
    union { float f; unsigned u; } v; v.f = x;
    unsigned r = (v.u + 0x7FFFu + ((v.u >> 16) & 1u)) >> 16;
    return (unsigned short)r;
}

// Kernel 1: colsum[j] += sum over an 8-row slab of nw. colsum pre-zeroed by memset.
__global__ void k_prep(const float* __restrict__ nw,
                       float* __restrict__ colsum) {
    int j  = blockIdx.x * 256 + threadIdx.x;
    int i0 = blockIdx.y * 8;
    if (j < NTOP) {
        float s = 0.f;
        int iend = min(i0 + 8, NTOP);
        for (int i = i0; i < iend; ++i) s += nw[(size_t)i * NTOP + j];
        atomicAdd(colsum + j, s);
    }
}

// Kernel 2: build B' in MFMA-fragment order (unchanged).
__global__ void k_vj(const float* __restrict__ V,
                     const float* __restrict__ noise,
                     const float* __restrict__ colsum,
                     unsigned short* __restrict__ Bp) {
    int t  = blockIdx.x * 256 + threadIdx.x;   // 0 .. 64*8*64-1 = 32767
    int nt = t >> 9;
    int s  = (t >> 6) & 7;
    int l  = t & 63;
    int lm = l & 15, lq = l >> 4;
    int n  = nt * 16 + lm;
    int k0 = s * 32 + lq * 8;
    union { short8 v; unsigned short us[8]; } pk;
    if (n < NTOP) {
        float cs = colsum[n];
        #pragma unroll
        for (int j = 0; j < 8; ++j) {
            int idx = n * KC + k0 + j;
            pk.us[j] = f2bf(V[idx] * cs + 0.1f * noise[idx]);
        }
    } else {
        #pragma unroll
        for (int j = 0; j < 8; ++j) pk.us[j] = 0;
    }
    reinterpret_cast<short8*>(Bp)[t] = pk.v;
}

// Kernel 2b: compress C -> row-major bitmask Cb[m][n/32] (5 MB). Unchanged.
__global__ __launch_bounds__(256) void k_cmask(const int* __restrict__ C,
                                               unsigned* __restrict__ Cb) {
    const int idx = blockIdx.x * 256 + threadIdx.x;   // < 40000*32 = 1,280,000
    const int m = idx >> 5, w = idx & 31;
    const int* p = C + (size_t)m * NTOP + w * 32;
    const int nbase = w * 32;
    unsigned word = 0;
    if (nbase + 32 <= NTOP) {
        #pragma unroll
        for (int j = 0; j < 32; j += 4) {
            i32x4 c4 = *reinterpret_cast<const i32x4*>(p + j);
            word |= (unsigned)(c4.x == 1) << (j + 0);
            word |= (unsigned)(c4.y == 1) << (j + 1);
            word |= (unsigned)(c4.z == 1) << (j + 2);
            word |= (unsigned)(c4.w == 1) << (j + 3);
        }
    } else {
        for (int j = 0; j < NTOP - nbase; ++j)
            word |= (unsigned)(p[j] == 1) << j;
    }
    Cb[idx] = word;
}

// ---- Flat macros on NAMED buffers (rule #20: no array-ref lambda params —
//      r12's PHASE lambda spilled 8.8 MB of ping-pong state to scratch). ----

#define LOADBF_M(nt_, B)                                                     \
    do { _Pragma("unroll")                                                   \
         for (int s_ = 0; s_ < 8; ++s_)                                      \
             B[s_] = Bf[(((nt_) * 8 + s_) << 6) + l]; } while (0)

#define LOADIT_M(nt_, RV, CW)                                                \
    do { const int nst_ = ((nt_) << 4) + (lq << 2);                          \
         const int ws_  = nst_ >> 5;                                         \
         if (nst_ < NTOP) {                                                  \
             RV[0] = *reinterpret_cast<const f32x4*>(R + rb0 + nst_);        \
             RV[1] = *reinterpret_cast<const f32x4*>(R + rb1 + nst_);        \
             RV[2] = *reinterpret_cast<const f32x4*>(R + rb2 + nst_);        \
             RV[3] = *reinterpret_cast<const f32x4*>(R + rb3 + nst_);        \
             CW[0] = Cb[cb0 + ws_]; CW[1] = Cb[cb1 + ws_];                   \
             CW[2] = Cb[cb2 + ws_]; CW[3] = Cb[cb3 + ws_];                   \
         } else {                                                            \
             _Pragma("unroll")                                               \
             for (int q_ = 0; q_ < 4; ++q_) {                                \
                 RV[q_] = (f32x4){0.f, 0.f, 0.f, 0.f}; CW[q_] = 0u; }        \
         } } while (0)

#define MFMA_M(B)                                                            \
    do { _Pragma("unroll")                                                   \
         for (int s_ = 0; s_ < 8; ++s_) {                                    \
             const short8 bfr_ = B[s_];                                      \
             const short8 a0_ = Afrag[0][s_][l];                             \
             const short8 a1_ = Afrag[1][s_][l];                             \
             const short8 a2_ = Afrag[2][s_][l];                             \
             const short8 a3_ = Afrag[3][s_][l];                             \
             acc[0] = __builtin_amdgcn_mfma_f32_16x16x32_bf16(bfr_, a0_, acc[0], 0, 0, 0); \
             acc[1] = __builtin_amdgcn_mfma_f32_16x16x32_bf16(bfr_, a1_, acc[1], 0, 0, 0); \
             acc[2] = __builtin_amdgcn_mfma_f32_16x16x32_bf16(bfr_, a2_, acc[2], 0, 0, 0); \
             acc[3] = __builtin_amdgcn_mfma_f32_16x16x32_bf16(bfr_, a3_, acc[3], 0, 0, 0); \
         } } while (0)

#define EPI_M(RV, CW, SH)                                                    \
    do { _Pragma("unroll")                                                   \
         for (int mt_ = 0; mt_ < 4; ++mt_) {                                 \
             const unsigned y_ = CW[mt_] >> (SH);                            \
             _Pragma("unroll")                                               \
             for (int r_ = 0; r_ < 4; ++r_) {                                \
                 float muv_ = 1.f / (1.f + __expf(-acc[mt_][r_]));           \
                 float d_   = RV[mt_][r_] - muv_;                            \
                 float lp_  = -50.f * d_ * d_ + 1.3836465597893728f;         \
                 if ((y_ >> r_) & 1u) lpsum += lp_;                          \
             } } } while (0)

// Kernel 3: r12 structure (MBLK=64, 4x B-reuse, bitmask C) with:
//  (a) flat named-buffer ping-pong (no spill),
//  (b) DEPTH-2 R/Cb prefetch: LOADIT issued AFTER the epilogue for nt+2 ->
//      every HBM load gets ~2 phases (~1200+cy) in flight,
//  (c) A-build async split: next group's stage loads issue before current
//      group's fragment compute; rawU stride padded 1280->1284 (bank conflicts).
__global__ __launch_bounds__(256, 3) void k_main(
    const float* __restrict__ U, const float* __restrict__ w5,
    const float* __restrict__ b1, const short8* __restrict__ Bf,
    const float* __restrict__ R, const unsigned* __restrict__ Cb,
    float* __restrict__ out)
{
    __shared__ short8 Afrag[4][8][64];   // [mt][s][ll] : 32 KB
    __shared__ float  rawU[4 * 1284];    // 4 U-rows, padded stride : ~20 KB

    const int tid  = threadIdx.x;
    const int wave = tid >> 6;
    const int l    = tid & 63;
    const int lm = l & 15;       // output m within 16-tile (col = lane&15)
    const int lq = l >> 4;       // quad: n-subblock of 4 (row = lq*4 + r)
    const int m0 = blockIdx.x * MBLK;

    const float w0 = w5[0], w1 = w5[1], w2 = w5[2], w3 = w5[3], w4 = w5[4];
    const float bb = b1[0];

    // ---- A-build: 16 groups of 4 rows, software-pipelined staging. ----
    const float* ub = U + (size_t)m0 * (KC * 5);
    {
        const int r4 = (tid * 4) / 1280;        // row within group (0..3)
        const int c4 = (tid * 4) % 1280;        // col within row
        f32x4 st[5];
        #pragma unroll
        for (int j = 0; j < 5; ++j) {
            const int idx = j * 1024 + tid * 4;
            st[j] = *reinterpret_cast<const f32x4*>(ub + idx);
        }
        for (int g = 0; g < 16; ++g) {
            // write staged regs -> padded rawU
            #pragma unroll
            for (int j = 0; j < 5; ++j) {
                const int idx = j * 1024 + tid * 4;
                const int rr = idx / 1280, cc = idx % 1280;
                *reinterpret_cast<f32x4*>(&rawU[rr * 1284 + cc]) = st[j];
            }
            __syncthreads();
            // issue NEXT group's loads (HBM latency hides under compute below)
            if (g < 15) {
                const float* src = ub + (size_t)(g + 1) * 5120;
                #pragma unroll
                for (int j = 0; j < 5; ++j)
                    st[j] = *reinterpret_cast<const f32x4*>(src + j * 1024 + tid * 4);
            }
            // compute fragments for group g from rawU
            if (tid < 128) {
                const int s   = tid >> 4;
                const int lqc = (tid >> 2) & 3;
                const int lmh = tid & 3;
                const int fi  = lmh * 1284 + s * 160 + lqc * 40;
                float u[40];
                #pragma unroll
                for (int i = 0; i < 10; ++i) {
                    f32x4 t = *reinterpret_cast<const f32x4*>(&rawU[fi + i * 4]);
                    u[i*4+0] = t.x; u[i*4+1] = t.y; u[i*4+2] = t.z; u[i*4+3] = t.w;
                }
                union { short8 v; unsigned short us[8]; } pk;
                #pragma unroll
                for (int j = 0; j < 8; ++j) {
                    float e = u[j*5+0]*w0 + u[j*5+1]*w1 + u[j*5+2]*w2
                            + u[j*5+3]*w3 + u[j*5+4]*w4 + bb;
                    pk.us[j] = f2bf(e);
                }
                const int mt = g >> 2;
                const int ll = lqc * 16 + ((g & 3) * 4 + lmh);
                Afrag[mt][s][ll] = pk.v;
            }
            __syncthreads();
        }
        (void)r4; (void)c4;
    }

    // Per-lane fixed row bases (m = m0 + mt*16 + lm).
    const size_t rb0 = (size_t)(m0 +  0 + lm) * NTOP;
    const size_t rb1 = (size_t)(m0 + 16 + lm) * NTOP;
    const size_t rb2 = (size_t)(m0 + 32 + lm) * NTOP;
    const size_t rb3 = (size_t)(m0 + 48 + lm) * NTOP;
    const size_t cb0 = (size_t)(m0 +  0 + lm) * 32;
    const size_t cb1 = (size_t)(m0 + 16 + lm) * 32;
    const size_t cb2 = (size_t)(m0 + 32 + lm) * 32;
    const size_t cb3 = (size_t)(m0 + 48 + lm) * 32;

    float lpsum = 0.f;
    const int nt0 = wave << 4;   // this wave's first 16-col n-tile (even)
    const int shE = lq << 2;
    const int shO = 16 + (lq << 2);

    short8 bf0[8], bf1[8];
    f32x4 rv0[4], rv1[4];
    unsigned cw0[4], cw1[4];

    LOADBF_M(nt0, bf0);
    LOADIT_M(nt0,     rv0, cw0);
    LOADIT_M(nt0 + 1, rv1, cw1);

    for (int it2 = 0; it2 < 8; ++it2) {
        const int ntE = nt0 + it2 * 2;
        f32x4 acc[4];

        // ---- even phase: compute ntE from bf0 / rv0 / cw0 ----
        __builtin_amdgcn_sched_barrier(0);
        LOADBF_M(ntE + 1, bf1);
        __builtin_amdgcn_sched_barrier(0);

        #pragma unroll
        for (int mt = 0; mt < 4; ++mt) acc[mt] = (f32x4){0.f, 0.f, 0.f, 0.f};
        MFMA_M(bf0);
        EPI_M(rv0, cw0, shE);

        __builtin_amdgcn_sched_barrier(0);
        if (it2 < 7) LOADIT_M(ntE + 2, rv0, cw0);   // depth-2: lands at it2+1 even
        __builtin_amdgcn_sched_barrier(0);

        // ---- odd phase: compute ntE+1 from bf1 / rv1 / cw1 ----
        __builtin_amdgcn_sched_barrier(0);
        if (it2 < 7) LOADBF_M(ntE + 2, bf0);
        __builtin_amdgcn_sched_barrier(0);

        #pragma unroll
        for (int mt = 0; mt < 4; ++mt) acc[mt] = (f32x4){0.f, 0.f, 0.f, 0.f};
        MFMA_M(bf1);
        EPI_M(rv1, cw1, shO);

        __builtin_amdgcn_sched_barrier(0);
        if (it2 < 7) LOADIT_M(ntE + 3, rv1, cw1);   // depth-2: lands at it2+1 odd
        __builtin_amdgcn_sched_barrier(0);
    }

    #pragma unroll
    for (int off = 32; off > 0; off >>= 1) lpsum += __shfl_down(lpsum, off);
    if (l == 0) atomicAdd(out, lpsum);
}

extern "C" void kernel_launch(void* const* d_in, const int* in_sizes, int n_in,
                              void* d_out, int out_size, void* d_ws, size_t ws_size,
                              hipStream_t stream) {
    const float* V     = (const float*)d_in[1];
    const float* R     = (const float*)d_in[2];
    const float* nw    = (const float*)d_in[3];
    const float* U     = (const float*)d_in[4];
    const float* w5    = (const float*)d_in[5];
    const float* b1    = (const float*)d_in[6];
    const float* noise = (const float*)d_in[7];
    const int*   C     = (const int*)d_in[8];
    float* out = (float*)d_out;

    // Workspace layout (ws >= 5.65 MB proven by r12's passing bitmask run):
    //   colsum: [0, 4000)         (padded to 8192)
    //   Bp    : [8192, 532480)    1024*256*2 = 524288 B
    //   Cb    : [532480, 5652480) 40000*32*4 = 5.12 MB
    float*          colsum = (float*)d_ws;
    unsigned short* Bp     = (unsigned short*)((char*)d_ws + 8192);
    unsigned*       Cb     = (unsigned*)((char*)d_ws + 532480);

    hipMemsetAsync(colsum, 0, NTOP * sizeof(float), stream);
    hipMemsetAsync(out, 0, sizeof(float), stream);
    hipLaunchKernelGGL(k_prep, dim3(4, 125), dim3(256), 0, stream, nw, colsum);
    hipLaunchKernelGGL(k_vj, dim3(128), dim3(256), 0, stream,
                       V, noise, colsum, Bp);
    hipLaunchKernelGGL(k_cmask, dim3(5000), dim3(256), 0, stream, C, Cb);
    hipLaunchKernelGGL(k_main, dim3(MROWS / MBLK), dim3(256), 0, stream,
                       U, w5, b1, (const short8*)Bp, R, Cb, out);
}

// Round 14
// 176.230 us; speedup vs baseline: 1.0572x; 1.0572x over previous
//
#include <hip/hip_runtime.h>
#include <hip/hip_bf16.h>

typedef __attribute__((ext_vector_type(8))) short short8;
typedef __attribute__((ext_vector_type(4))) float f32x4;
typedef __attribute__((ext_vector_type(4))) int   i32x4;

#define NTOP 1000
#define KC   256
#define MROWS 40000
#define MBLK  64

static __device__ __forceinline__ unsigned short f2bf(float x) {
    union { float f; unsigned u; } v; v.f = x;
    unsigned r = (v.u + 0x7FFFu + ((v.u >> 16) & 1u)) >> 16;
    return (unsigned short)r;
}

// Kernel 1: colsum[j] += sum over an 8-row slab of nw. colsum pre-zeroed by memset.
__global__ void k_prep(const float* __restrict__ nw,
                       float* __restrict__ colsum) {
    int j  = blockIdx.x * 256 + threadIdx.x;
    int i0 = blockIdx.y * 8;
    if (j < NTOP) {
        float s = 0.f;
        int iend = min(i0 + 8, NTOP);
        for (int i = i0; i < iend; ++i) s += nw[(size_t)i * NTOP + j];
        atomicAdd(colsum + j, s);
    }
}

// Kernel 2: build B' in MFMA-fragment order (unchanged).
__global__ void k_vj(const float* __restrict__ V,
                     const float* __restrict__ noise,
                     const float* __restrict__ colsum,
                     unsigned short* __restrict__ Bp) {
    int t  = blockIdx.x * 256 + threadIdx.x;   // 0 .. 64*8*64-1 = 32767
    int nt = t >> 9;
    int s  = (t >> 6) & 7;
    int l  = t & 63;
    int lm = l & 15, lq = l >> 4;
    int n  = nt * 16 + lm;
    int k0 = s * 32 + lq * 8;
    union { short8 v; unsigned short us[8]; } pk;
    if (n < NTOP) {
        float cs = colsum[n];
        #pragma unroll
        for (int j = 0; j < 8; ++j) {
            int idx = n * KC + k0 + j;
            pk.us[j] = f2bf(V[idx] * cs + 0.1f * noise[idx]);
        }
    } else {
        #pragma unroll
        for (int j = 0; j < 8; ++j) pk.us[j] = 0;
    }
    reinterpret_cast<short8*>(Bp)[t] = pk.v;
}

// Kernel 2b: compress C -> row-major bitmask Cb[m][n/32] (5 MB). Proven in r12.
__global__ __launch_bounds__(256) void k_cmask(const int* __restrict__ C,
                                               unsigned* __restrict__ Cb) {
    const int idx = blockIdx.x * 256 + threadIdx.x;   // < 40000*32 = 1,280,000
    const int m = idx >> 5, w = idx & 31;
    const int* p = C + (size_t)m * NTOP + w * 32;
    const int nbase = w * 32;
    unsigned word = 0;
    if (nbase + 32 <= NTOP) {
        #pragma unroll
        for (int j = 0; j < 32; j += 4) {
            i32x4 c4 = *reinterpret_cast<const i32x4*>(p + j);
            word |= (unsigned)(c4.x == 1) << (j + 0);
            word |= (unsigned)(c4.y == 1) << (j + 1);
            word |= (unsigned)(c4.z == 1) << (j + 2);
            word |= (unsigned)(c4.w == 1) << (j + 3);
        }
    } else {
        for (int j = 0; j < NTOP - nbase; ++j)
            word |= (unsigned)(p[j] == 1) << j;
    }
    Cb[idx] = word;
}

// Kernel 3: r11's proven no-spill k_main (MBLK=64, 4x B-reuse, Bf reg
// double-buffer with per-iter copies, depth-1 pinned prefetch) with ONE change:
// C read as bitmask words from Cb (L2-resident 5MB) instead of 160MB of i32x4.
// Register state DROPS vs r11 (cv 32 VGPRs -> cw 8), so no new spill risk.
// (r12/r13 lesson: bitmask k_main is worth ~55us prof, but their phase/depth-2
// rewrites spilled 8MB and ate the win. Minimal diff this time.)
__global__ __launch_bounds__(256, 3) void k_main(
    const float* __restrict__ U, const float* __restrict__ w5,
    const float* __restrict__ b1, const short8* __restrict__ Bf,
    const float* __restrict__ R, const unsigned* __restrict__ Cb,
    float* __restrict__ out)
{
    __shared__ short8 Afrag[4][8][64];   // [mt][s][ll] : 32 KB
    __shared__ float  rawU[5120];        // 4 U-rows    : 20 KB

    const int tid  = threadIdx.x;
    const int wave = tid >> 6;
    const int l    = tid & 63;
    const int lm = l & 15;       // output m within 16-tile (col = lane&15)
    const int lq = l >> 4;       // quad: n-subblock of 4 (row = lq*4 + r)
    const int m0 = blockIdx.x * MBLK;

    const float w0 = w5[0], w1 = w5[1], w2 = w5[2], w3 = w5[3], w4 = w5[4];
    const float bb = b1[0];

    // ---- A-build: 16 groups of 4 rows. Stage coalesced, compute from LDS. ----
    const float* ub = U + (size_t)m0 * (KC * 5);
    for (int g = 0; g < 16; ++g) {
        const float* src = ub + (size_t)g * 5120;
        #pragma unroll
        for (int j = 0; j < 5; ++j) {
            const int idx = j * 1024 + tid * 4;
            *reinterpret_cast<f32x4*>(&rawU[idx]) =
                *reinterpret_cast<const f32x4*>(src + idx);
        }
        __syncthreads();
        if (tid < 128) {   // 128 fragment-chunks for these 4 rows
            const int s   = tid >> 4;
            const int lqc = (tid >> 2) & 3;
            const int lmh = tid & 3;
            const int fi  = lmh * 1280 + s * 160 + lqc * 40;
            float u[40];
            #pragma unroll
            for (int i = 0; i < 10; ++i) {
                f32x4 t = *reinterpret_cast<const f32x4*>(&rawU[fi + i * 4]);
                u[i*4+0] = t.x; u[i*4+1] = t.y; u[i*4+2] = t.z; u[i*4+3] = t.w;
            }
            union { short8 v; unsigned short us[8]; } pk;
            #pragma unroll
            for (int j = 0; j < 8; ++j) {
                float e = u[j*5+0]*w0 + u[j*5+1]*w1 + u[j*5+2]*w2
                        + u[j*5+3]*w3 + u[j*5+4]*w4 + bb;
                pk.us[j] = f2bf(e);
            }
            const int mt = g >> 2;
            const int ll = lqc * 16 + ((g & 3) * 4 + lmh);
            Afrag[mt][s][ll] = pk.v;
        }
        __syncthreads();
    }

    // Per-lane fixed row bases (m = m0 + mt*16 + lm).
    const size_t rb0 = (size_t)(m0 +  0 + lm) * NTOP;
    const size_t rb1 = (size_t)(m0 + 16 + lm) * NTOP;
    const size_t rb2 = (size_t)(m0 + 32 + lm) * NTOP;
    const size_t rb3 = (size_t)(m0 + 48 + lm) * NTOP;
    const size_t cb0 = (size_t)(m0 +  0 + lm) * 32;
    const size_t cb1 = (size_t)(m0 + 16 + lm) * 32;
    const size_t cb2 = (size_t)(m0 + 32 + lm) * 32;
    const size_t cb3 = (size_t)(m0 + 48 + lm) * 32;

    // Load R dwordx4 + mask words for one 16-col n-tile, all 4 m-tiles.
    auto LOADIT = [&](int nt16_, f32x4* rv_, unsigned* cw_) {
        const int nst = (nt16_ << 4) + (lq << 2);
        if (nst < NTOP) {
            const int ws = nst >> 5;
            rv_[0] = *reinterpret_cast<const f32x4*>(R + rb0 + nst);
            rv_[1] = *reinterpret_cast<const f32x4*>(R + rb1 + nst);
            rv_[2] = *reinterpret_cast<const f32x4*>(R + rb2 + nst);
            rv_[3] = *reinterpret_cast<const f32x4*>(R + rb3 + nst);
            cw_[0] = Cb[cb0 + ws];
            cw_[1] = Cb[cb1 + ws];
            cw_[2] = Cb[cb2 + ws];
            cw_[3] = Cb[cb3 + ws];
        } else {
            #pragma unroll
            for (int q = 0; q < 4; ++q) {
                rv_[q] = (f32x4){0.f, 0.f, 0.f, 0.f};
                cw_[q] = 0u;
            }
        }
    };

    // Load the 8 Bf fragments of one n-tile into registers.
    auto LOADBF = [&](int nt16_, short8* b_) {
        #pragma unroll
        for (int s = 0; s < 8; ++s)
            b_[s] = Bf[((nt16_ * 8 + s) << 6) + l];
    };

    float lpsum = 0.f;
    const int nt0 = wave << 4;   // this wave's first 16-col n-tile

    short8 bfc[8], bfn[8];
    f32x4 rv[4]; unsigned cw[4];
    LOADBF(nt0, bfc);
    LOADIT(nt0, rv, cw);

    for (int it = 0; it < 16; ++it) {
        const int nt16 = nt0 + it;

        // ---- pinned issue slot: NEXT n-tile's Bf (before this tile's MFMAs) ----
        __builtin_amdgcn_sched_barrier(0);
        if (it < 15) LOADBF(nt16 + 1, bfn);
        __builtin_amdgcn_sched_barrier(0);

        f32x4 acc[4];
        #pragma unroll
        for (int mt = 0; mt < 4; ++mt) acc[mt] = (f32x4){0.f, 0.f, 0.f, 0.f};

        #pragma unroll
        for (int s = 0; s < 8; ++s) {
            const short8 bfr = bfc[s];
            const short8 a0 = Afrag[0][s][l];
            const short8 a1 = Afrag[1][s][l];
            const short8 a2 = Afrag[2][s][l];
            const short8 a3 = Afrag[3][s][l];
            // swapped operands: bfr rows (n), A cols (m). One Bf load -> 4 MFMAs.
            acc[0] = __builtin_amdgcn_mfma_f32_16x16x32_bf16(bfr, a0, acc[0], 0, 0, 0);
            acc[1] = __builtin_amdgcn_mfma_f32_16x16x32_bf16(bfr, a1, acc[1], 0, 0, 0);
            acc[2] = __builtin_amdgcn_mfma_f32_16x16x32_bf16(bfr, a2, acc[2], 0, 0, 0);
            acc[3] = __builtin_amdgcn_mfma_f32_16x16x32_bf16(bfr, a3, acc[3], 0, 0, 0);
        }

        f32x4 rv2[4]; unsigned cw2[4];

        // ---- pinned issue slot: next n-tile's R/Cb ----
        __builtin_amdgcn_sched_barrier(0);
        if (it < 15) LOADIT(nt16 + 1, rv2, cw2);
        __builtin_amdgcn_sched_barrier(0);

        // Consume: n = nt16*16 + lq*4 + r, m = m0 + mt*16 + lm.
        // Mask bit for n: word nst>>5, bit (nt16&1)*16 + lq*4 + r.
        const int sh = ((nt16 & 1) << 4) + (lq << 2);
        #pragma unroll
        for (int mt = 0; mt < 4; ++mt) {
            const unsigned y = cw[mt] >> sh;
            #pragma unroll
            for (int r = 0; r < 4; ++r) {
                float muv = 1.f / (1.f + __expf(-acc[mt][r]));
                float d   = rv[mt][r] - muv;
                float lp  = -50.f * d * d + 1.3836465597893728f;
                if ((y >> r) & 1u) lpsum += lp;
            }
        }

        if (it < 15) {
            #pragma unroll
            for (int s = 0; s < 8; ++s) bfc[s] = bfn[s];
            rv[0] = rv2[0]; cw[0] = cw2[0];
            rv[1] = rv2[1]; cw[1] = cw2[1];
            rv[2] = rv2[2]; cw[2] = cw2[2];
            rv[3] = rv2[3]; cw[3] = cw2[3];
        }
    }

    #pragma unroll
    for (int off = 32; off > 0; off >>= 1) lpsum += __shfl_down(lpsum, off);
    if (l == 0) atomicAdd(out, lpsum);
}

extern "C" void kernel_launch(void* const* d_in, const int* in_sizes, int n_in,
                              void* d_out, int out_size, void* d_ws, size_t ws_size,
                              hipStream_t stream) {
    const float* V     = (const float*)d_in[1];
    const float* R     = (const float*)d_in[2];
    const float* nw    = (const float*)d_in[3];
    const float* U     = (const float*)d_in[4];
    const float* w5    = (const float*)d_in[5];
    const float* b1    = (const float*)d_in[6];
    const float* noise = (const float*)d_in[7];
    const int*   C     = (const int*)d_in[8];
    float* out = (float*)d_out;

    // Workspace layout (ws >= 5.65 MB proven by r12/r13 passing runs):
    //   colsum: [0, 4000)         (padded to 8192)
    //   Bp    : [8192, 532480)    1024*256*2 = 524288 B
    //   Cb    : [532480, 5652480) 40000*32*4 = 5.12 MB
    float*          colsum = (float*)d_ws;
    unsigned short* Bp     = (unsigned short*)((char*)d_ws + 8192);
    unsigned*       Cb     = (unsigned*)((char*)d_ws + 532480);

    hipMemsetAsync(colsum, 0, NTOP * sizeof(float), stream);
    hipMemsetAsync(out, 0, sizeof(float), stream);
    hipLaunchKernelGGL(k_prep, dim3(4, 125), dim3(256), 0, stream, nw, colsum);
    hipLaunchKernelGGL(k_vj, dim3(128), dim3(256), 0, stream,
                       V, noise, colsum, Bp);
    hipLaunchKernelGGL(k_cmask, dim3(5000), dim3(256), 0, stream, C, Cb);
    hipLaunchKernelGGL(k_main, dim3(MROWS / MBLK), dim3(256), 0, stream,
                       U, w5, b1, (const short8*)Bp, R, Cb, out);
}